// Round 4
// baseline (2803.129 us; speedup 1.0000x reference)
//
#include <hip/hip_runtime.h>
#include <cstdint>

#define LEAKY 0.2f
#define LN_EPS 1e-5f

typedef __attribute__((ext_vector_type(8))) short short8;   // 8 x bf16 (4 VGPR)
typedef __attribute__((ext_vector_type(4))) float f32x4;    // MFMA accum

__device__ __forceinline__ ushort bf16_rne(float x) {
    unsigned u = __float_as_uint(x);
    unsigned r = (u + 0x7fffu + ((u >> 16) & 1u)) >> 16;
    return (ushort)r;
}
__device__ __forceinline__ float bf16_to_f(ushort h) {
    return __uint_as_float(((unsigned)h) << 16);
}

// ---------------------------------------------------------------------------
// CSR build: histogram, hierarchical exclusive scan, scatter
// ---------------------------------------------------------------------------
__global__ void hist_kernel(const int* __restrict__ ei, int er, int etot,
                            int* __restrict__ deg) {
    int e = blockIdx.x * blockDim.x + threadIdx.x;
    if (e >= etot) return;
    int dst = (e < er) ? ei[er + e] : (e - er);   // self-loops appended
    atomicAdd(&deg[dst], 1);
}

__global__ __launch_bounds__(1024) void scanA(const int* __restrict__ deg,
                                              int* __restrict__ escan,
                                              int* __restrict__ bsum, int n) {
    __shared__ int wsum[16], wpre[16];
    const int lane = threadIdx.x & 63, wv = threadIdx.x >> 6;
    const int i = blockIdx.x * 1024 + threadIdx.x;
    int v = (i < n) ? deg[i] : 0;
    int x = v;
#pragma unroll
    for (int off = 1; off < 64; off <<= 1) {
        int y = __shfl_up(x, off, 64);
        if (lane >= off) x += y;
    }
    if (lane == 63) wsum[wv] = x;
    __syncthreads();
    if (wv == 0) {
        int s = (lane < 16) ? wsum[lane] : 0;
#pragma unroll
        for (int off = 1; off < 16; off <<= 1) {
            int y = __shfl_up(s, off, 64);
            if (lane >= off) s += y;
        }
        if (lane < 16) wpre[lane] = s;
    }
    __syncthreads();
    int excl = x - v + (wv ? wpre[wv - 1] : 0);
    if (i < n) escan[i] = excl;
    if (threadIdx.x == 1023) bsum[blockIdx.x] = wpre[15];
}

__global__ __launch_bounds__(1024) void scanB(const int* __restrict__ bsum,
                                              int* __restrict__ bpre, int nb,
                                              int* __restrict__ offs, int n) {
    __shared__ int wsum[16], wpre[16];
    const int lane = threadIdx.x & 63, wv = threadIdx.x >> 6;
    const int i = threadIdx.x;
    int v = (i < nb) ? bsum[i] : 0;
    int x = v;
#pragma unroll
    for (int off = 1; off < 64; off <<= 1) {
        int y = __shfl_up(x, off, 64);
        if (lane >= off) x += y;
    }
    if (lane == 63) wsum[wv] = x;
    __syncthreads();
    if (wv == 0) {
        int s = (lane < 16) ? wsum[lane] : 0;
#pragma unroll
        for (int off = 1; off < 16; off <<= 1) {
            int y = __shfl_up(s, off, 64);
            if (lane >= off) s += y;
        }
        if (lane < 16) wpre[lane] = s;
    }
    __syncthreads();
    if (i < nb) bpre[i] = x - v + (wv ? wpre[wv - 1] : 0);
    if (threadIdx.x == 1023) offs[n] = wpre[15];
}

__global__ void scanC(const int* __restrict__ escan, const int* __restrict__ bpre,
                      int* __restrict__ offs, int* __restrict__ woff, int n) {
    int i = blockIdx.x * 256 + threadIdx.x;
    if (i >= n) return;
    int o = escan[i] + bpre[i >> 10];
    offs[i] = o;
    woff[i] = o;
}

__global__ void fill_kernel(const int* __restrict__ ei, int er, int etot,
                            int* __restrict__ woff, int* __restrict__ colv) {
    int e = blockIdx.x * blockDim.x + threadIdx.x;
    if (e >= etot) return;
    int src, dst;
    if (e < er) { src = ei[e]; dst = ei[er + e]; }
    else        { src = dst = e - er; }
    int pos = atomicAdd(&woff[dst], 1);
    colv[pos] = src;
}

// ---------------------------------------------------------------------------
// W -> per-MFMA-fragment bf16 hi/lo layout so gemm B-loads are coalesced.
// Wf[colblk(16)][ks(4)][lane(64)][j(8)]: value W[k][col],
//   col = colblk*16 + (lane&15), k = ks*32 + (lane>>4)*8 + j.
// colblk 0..7 = Wl cols, 8..15 = Wr cols.
// ---------------------------------------------------------------------------
__global__ void cvt_w(const float* __restrict__ Wl, const float* __restrict__ Wr,
                      ushort* __restrict__ Whi, ushort* __restrict__ Wlo) {
    int t = blockIdx.x * 256 + threadIdx.x;     // 0..32767
    int colblk = t >> 11;
    int ks = (t >> 9) & 3;
    int lane = (t >> 3) & 63;
    int j = t & 7;
    int col = colblk * 16 + (lane & 15);
    int k = ks * 32 + (lane >> 4) * 8 + j;
    float v = (col < 128) ? Wl[(size_t)k * 128 + col]
                          : Wr[(size_t)k * 128 + (col - 128)];
    ushort h = bf16_rne(v);
    Whi[t] = h;
    Wlo[t] = bf16_rne(v - bf16_to_f(h));
}

// ---------------------------------------------------------------------------
// Dual GEMM via split-bf16 MFMA. Block = 4 waves, 64-row tile.
// X tile staged in LDS (coalesced, XOR-swizzled 16B slots -> 2-way ds_read).
// B frags from pre-swizzled Wf (64-lane contiguous 1KB loads, L2-hot).
// wave w: cols [64w, 64w+64); waves 0,1 -> Ol, waves 2,3 -> Or.
// ---------------------------------------------------------------------------
__global__ __launch_bounds__(256) void gemm_mfma(
    const float* __restrict__ X,
    const ushort* __restrict__ Wfhi, const ushort* __restrict__ Wflo,
    float* __restrict__ Ol, float* __restrict__ Or, int nrows) {
    __shared__ float xs[64 * 128];              // 32 KiB, slot = row*32 + (kc^(row&7))
    const int t = threadIdx.x;
    const int wave = t >> 6, lane = t & 63;
    const int m0 = blockIdx.x * 64;
    {   // stage X tile: 2048 float4, 8 per thread, coalesced
        const float4* Xv = (const float4*)X + (size_t)m0 * 32;
        float4* xsv = (float4*)xs;
#pragma unroll
        for (int i = 0; i < 8; ++i) {
            int idx = i * 256 + t;
            int row = idx >> 5, kc = idx & 31;
            float4 v = {0.f, 0.f, 0.f, 0.f};
            if (m0 + row < nrows) v = Xv[idx];
            xsv[row * 32 + (kc ^ (row & 7))] = v;
        }
    }
    __syncthreads();

    const int lrow = lane & 15;
    const int lkc = (lane >> 4) * 2;            // 16B-slot offset within ks block
    f32x4 acc[4][4];
#pragma unroll
    for (int mt = 0; mt < 4; ++mt)
#pragma unroll
        for (int nt = 0; nt < 4; ++nt) acc[mt][nt] = (f32x4){0.f, 0.f, 0.f, 0.f};

#pragma unroll
    for (int ks = 0; ks < 4; ++ks) {
        short8 bhi[4], blo[4];
#pragma unroll
        for (int nt = 0; nt < 4; ++nt) {
            size_t off = (((size_t)(wave * 4 + nt) * 4 + ks) * 64 + lane) * 8;
            bhi[nt] = *(const short8*)&Wfhi[off];
            blo[nt] = *(const short8*)&Wflo[off];
        }
        short8 ahi[4], alo[4];
#pragma unroll
        for (int mt = 0; mt < 4; ++mt) {
            const int row = mt * 16 + lrow;
            const int kc0 = ks * 8 + lkc;
            float4 v0 = ((const float4*)xs)[row * 32 + (kc0 ^ (row & 7))];
            float4 v1 = ((const float4*)xs)[row * 32 + ((kc0 + 1) ^ (row & 7))];
            float e[8];
            e[0] = v0.x; e[1] = v0.y; e[2] = v0.z; e[3] = v0.w;
            e[4] = v1.x; e[5] = v1.y; e[6] = v1.z; e[7] = v1.w;
#pragma unroll
            for (int j = 0; j < 8; ++j) {
                ushort h = bf16_rne(e[j]);
                ahi[mt][j] = (short)h;
                alo[mt][j] = (short)bf16_rne(e[j] - bf16_to_f(h));
            }
        }
#pragma unroll
        for (int nt = 0; nt < 4; ++nt) {
#pragma unroll
            for (int mt = 0; mt < 4; ++mt) {
                acc[mt][nt] = __builtin_amdgcn_mfma_f32_16x16x32_bf16(
                    alo[mt], bhi[nt], acc[mt][nt], 0, 0, 0);
                acc[mt][nt] = __builtin_amdgcn_mfma_f32_16x16x32_bf16(
                    ahi[mt], blo[nt], acc[mt][nt], 0, 0, 0);
                acc[mt][nt] = __builtin_amdgcn_mfma_f32_16x16x32_bf16(
                    ahi[mt], bhi[nt], acc[mt][nt], 0, 0, 0);
            }
        }
    }
    // Epilogue. C/D frag: col = lane&15, row = (lane>>4)*4 + i  [m89 layout].
    float* __restrict__ O = (wave < 2) ? Ol : Or;
    const int cbase = (wave * 64) & 127;
    const int crow0 = (lane >> 4) * 4;
#pragma unroll
    for (int mt = 0; mt < 4; ++mt) {
#pragma unroll
        for (int i = 0; i < 4; ++i) {
            const int row = m0 + mt * 16 + crow0 + i;
            if (row >= nrows) continue;
#pragma unroll
            for (int nt = 0; nt < 4; ++nt) {
                const int col = cbase + nt * 16 + lrow;
                O[(size_t)row * 128 + col] = acc[mt][nt][i];
            }
        }
    }
}

// ---------------------------------------------------------------------------
// Fused GATv2 aggregation + bias + ELU + residual + LayerNorm.
// One wave per destination node, dynamically work-stolen via global counter.
// ---------------------------------------------------------------------------
__global__ __launch_bounds__(256) void gat_agg(
    const float* __restrict__ xl, const float* __restrict__ xr,
    const int* __restrict__ offs, const int* __restrict__ colv,
    const float* __restrict__ att,
    const float* __restrict__ bias, const float* __restrict__ gamma,
    const float* __restrict__ beta, const float* __restrict__ resid,
    float* __restrict__ out, int* __restrict__ ctr, int nnode) {
    const int lane = threadIdx.x & 63;
    const float2* __restrict__ xlb = (const float2*)xl + lane;
    const float2 att2 = ((const float2*)att)[lane];
    const float2 b2 = ((const float2*)bias)[lane];
    const float2 g2 = ((const float2*)gamma)[lane];
    const float2 be2 = ((const float2*)beta)[lane];
    for (;;) {
        int gid;
        if (lane == 0) gid = atomicAdd(ctr, 1);
        gid = __shfl(gid, 0);
        if (gid >= nnode) return;
        const float2 xr2 = ((const float2*)xr)[(size_t)gid * 64 + lane];
        float den = 0.f, acc0 = 0.f, acc1 = 0.f;
        int e = offs[gid];
        const int e1 = offs[gid + 1];
        for (; e + 4 <= e1; e += 4) {   // 4-edge unroll: MLP on the gather
            int s0 = colv[e], s1 = colv[e + 1], s2 = colv[e + 2], s3 = colv[e + 3];
            float2 a0 = xlb[(size_t)s0 * 64];
            float2 a1 = xlb[(size_t)s1 * 64];
            float2 a2 = xlb[(size_t)s2 * 64];
            float2 a3 = xlb[(size_t)s3 * 64];
            float m0x = a0.x + xr2.x, m0y = a0.y + xr2.y;
            float m1x = a1.x + xr2.x, m1y = a1.y + xr2.y;
            float m2x = a2.x + xr2.x, m2y = a2.y + xr2.y;
            float m3x = a3.x + xr2.x, m3y = a3.y + xr2.y;
            m0x = fmaxf(m0x, LEAKY * m0x); m0y = fmaxf(m0y, LEAKY * m0y);
            m1x = fmaxf(m1x, LEAKY * m1x); m1y = fmaxf(m1y, LEAKY * m1y);
            m2x = fmaxf(m2x, LEAKY * m2x); m2y = fmaxf(m2y, LEAKY * m2y);
            m3x = fmaxf(m3x, LEAKY * m3x); m3y = fmaxf(m3y, LEAKY * m3y);
            float p0 = m0x * att2.x + m0y * att2.y;
            float p1 = m1x * att2.x + m1y * att2.y;
            float p2 = m2x * att2.x + m2y * att2.y;
            float p3 = m3x * att2.x + m3y * att2.y;
            p0 += __shfl_xor(p0, 1); p0 += __shfl_xor(p0, 2); p0 += __shfl_xor(p0, 4);
            p1 += __shfl_xor(p1, 1); p1 += __shfl_xor(p1, 2); p1 += __shfl_xor(p1, 4);
            p2 += __shfl_xor(p2, 1); p2 += __shfl_xor(p2, 2); p2 += __shfl_xor(p2, 4);
            p3 += __shfl_xor(p3, 1); p3 += __shfl_xor(p3, 2); p3 += __shfl_xor(p3, 4);
            float ex0 = __expf(p0), ex1 = __expf(p1);
            float ex2 = __expf(p2), ex3 = __expf(p3);
            den += (ex0 + ex1) + (ex2 + ex3);
            acc0 += a0.x * ex0 + a1.x * ex1 + a2.x * ex2 + a3.x * ex3;
            acc1 += a0.y * ex0 + a1.y * ex1 + a2.y * ex2 + a3.y * ex3;
        }
        for (; e < e1; ++e) {
            int s0 = colv[e];
            float2 a0 = xlb[(size_t)s0 * 64];
            float m0x = a0.x + xr2.x, m0y = a0.y + xr2.y;
            m0x = fmaxf(m0x, LEAKY * m0x);
            m0y = fmaxf(m0y, LEAKY * m0y);
            float p0 = m0x * att2.x + m0y * att2.y;
            p0 += __shfl_xor(p0, 1); p0 += __shfl_xor(p0, 2); p0 += __shfl_xor(p0, 4);
            float ex0 = __expf(p0);
            den += ex0;
            acc0 += a0.x * ex0;
            acc1 += a0.y * ex0;
        }
        float inv_den = 1.f / den;
        float v0 = acc0 * inv_den + b2.x;
        float v1 = acc1 * inv_den + b2.y;
        v0 = v0 > 0.f ? v0 : expm1f(v0);     // ELU (alpha=1)
        v1 = v1 > 0.f ? v1 : expm1f(v1);
        const float2 r2 = ((const float2*)resid)[(size_t)gid * 64 + lane];
        float t0 = v0 + r2.x, t1 = v1 + r2.y;
        float s = t0 + t1, ss = t0 * t0 + t1 * t1;
#pragma unroll
        for (int m = 1; m < 64; m <<= 1) {
            s += __shfl_xor(s, m);
            ss += __shfl_xor(ss, m);
        }
        const float mu = s * 0.0078125f;
        const float var = ss * 0.0078125f - mu * mu;
        const float iv = rsqrtf(var + LN_EPS);
        float2 o;
        o.x = (t0 - mu) * iv * g2.x + be2.x;
        o.y = (t1 - mu) * iv * g2.y + be2.y;
        ((float2*)out)[(size_t)gid * 64 + lane] = o;
    }
}

// ---------------------------------------------------------------------------
extern "C" void kernel_launch(void* const* d_in, const int* in_sizes, int n_in,
                              void* d_out, int out_size, void* d_ws, size_t ws_size,
                              hipStream_t stream) {
    const float* x   = (const float*)d_in[0];
    const int*   ei  = (const int*)d_in[1];
    const float* Wl0 = (const float*)d_in[2];
    const float* Wr0 = (const float*)d_in[3];
    const float* at0 = (const float*)d_in[4];
    const float* b0  = (const float*)d_in[5];
    const float* g0  = (const float*)d_in[6];
    const float* be0 = (const float*)d_in[7];
    const float* Wl1 = (const float*)d_in[8];
    const float* Wr1 = (const float*)d_in[9];
    const float* at1 = (const float*)d_in[10];
    const float* b1  = (const float*)d_in[11];
    const float* g1  = (const float*)d_in[12];
    const float* be1 = (const float*)d_in[13];

    const int NF = in_sizes[0];        // N*128
    const int n  = NF / 128;           // nodes
    const int er = in_sizes[1] / 2;    // raw edges
    const int etot = er + n;           // + self-loops
    const int nb = (n + 1023) / 1024;  // scan blocks

    float* A    = (float*)d_ws;        // xl  (N*128)
    float* B    = A + (size_t)NF;      // xr  (N*128)
    ushort* Whi = (ushort*)(B + (size_t)NF);   // 32768 bf16 hi (frag layout)
    ushort* Wlo = Whi + 32768;                 // 32768 bf16 lo
    int* deg    = (int*)(Wlo + 32768);
    int* ctr    = deg + n;             // [0]=layer1, [1]=layer2 work counters
    int* woff   = ctr + 2;
    int* offs   = woff + n;
    int* escan  = offs + (n + 1);
    int* bsum   = escan + n;
    int* bpre   = bsum + 1024;
    int* colv   = bpre + 1024;
    float* C    = (float*)d_out;       // layer-1 output / residual / final out

    // ---- CSR build (shared by both layers); also zeroes work counters ----
    hipMemsetAsync(deg, 0, (size_t)(n + 2) * sizeof(int), stream);
    hist_kernel<<<(etot + 255) / 256, 256, 0, stream>>>(ei, er, etot, deg);
    scanA<<<nb, 1024, 0, stream>>>(deg, escan, bsum, n);
    scanB<<<1, 1024, 0, stream>>>(bsum, bpre, nb, offs, n);
    scanC<<<(n + 255) / 256, 256, 0, stream>>>(escan, bpre, offs, woff, n);
    fill_kernel<<<(etot + 255) / 256, 256, 0, stream>>>(ei, er, etot, woff, colv);

    const int gblk = (n + 63) / 64;

    // ---- layer 1 ----
    cvt_w<<<128, 256, 0, stream>>>(Wl0, Wr0, Whi, Wlo);
    gemm_mfma<<<gblk, 256, 0, stream>>>(x, Whi, Wlo, A, B, n);
    gat_agg<<<2048, 256, 0, stream>>>(A, B, offs, colv, at0, b0, g0, be0,
                                      x, C, ctr + 0, n);
    // ---- layer 2 ----
    cvt_w<<<128, 256, 0, stream>>>(Wl1, Wr1, Whi, Wlo);
    gemm_mfma<<<gblk, 256, 0, stream>>>(C, Whi, Wlo, A, B, n);
    gat_agg<<<2048, 256, 0, stream>>>(A, B, offs, colv, at1, b1, g1, be1,
                                      C, C, ctr + 1, n);
}

// Round 6
// 587.117 us; speedup vs baseline: 4.7744x; 4.7744x over previous
//
#include <hip/hip_runtime.h>
#include <cstdint>

#define LEAKY 0.2f
#define LN_EPS 1e-5f

typedef __attribute__((ext_vector_type(8))) short short8;   // 8 x bf16 (4 VGPR)
typedef __attribute__((ext_vector_type(4))) float f32x4;    // MFMA accum

__device__ __forceinline__ ushort bf16_rne(float x) {
    unsigned u = __float_as_uint(x);
    unsigned r = (u + 0x7fffu + ((u >> 16) & 1u)) >> 16;
    return (ushort)r;
}
__device__ __forceinline__ float bf16_to_f(ushort h) {
    return __uint_as_float(((unsigned)h) << 16);
}

// ---------------------------------------------------------------------------
// CSR build: histogram, hierarchical exclusive scan, scatter
// ---------------------------------------------------------------------------
__global__ void hist_kernel(const int* __restrict__ ei, int er, int etot,
                            int* __restrict__ deg) {
    int e = blockIdx.x * blockDim.x + threadIdx.x;
    if (e >= etot) return;
    int dst = (e < er) ? ei[er + e] : (e - er);   // self-loops appended
    atomicAdd(&deg[dst], 1);
}

__global__ __launch_bounds__(1024) void scanA(const int* __restrict__ deg,
                                              int* __restrict__ escan,
                                              int* __restrict__ bsum, int n) {
    __shared__ int wsum[16], wpre[16];
    const int lane = threadIdx.x & 63, wv = threadIdx.x >> 6;
    const int i = blockIdx.x * 1024 + threadIdx.x;
    int v = (i < n) ? deg[i] : 0;
    int x = v;
#pragma unroll
    for (int off = 1; off < 64; off <<= 1) {
        int y = __shfl_up(x, off, 64);
        if (lane >= off) x += y;
    }
    if (lane == 63) wsum[wv] = x;
    __syncthreads();
    if (wv == 0) {
        int s = (lane < 16) ? wsum[lane] : 0;
#pragma unroll
        for (int off = 1; off < 16; off <<= 1) {
            int y = __shfl_up(s, off, 64);
            if (lane >= off) s += y;
        }
        if (lane < 16) wpre[lane] = s;
    }
    __syncthreads();
    int excl = x - v + (wv ? wpre[wv - 1] : 0);
    if (i < n) escan[i] = excl;
    if (threadIdx.x == 1023) bsum[blockIdx.x] = wpre[15];
}

__global__ __launch_bounds__(1024) void scanB(const int* __restrict__ bsum,
                                              int* __restrict__ bpre, int nb,
                                              int* __restrict__ offs, int n) {
    __shared__ int wsum[16], wpre[16];
    const int lane = threadIdx.x & 63, wv = threadIdx.x >> 6;
    const int i = threadIdx.x;
    int v = (i < nb) ? bsum[i] : 0;
    int x = v;
#pragma unroll
    for (int off = 1; off < 64; off <<= 1) {
        int y = __shfl_up(x, off, 64);
        if (lane >= off) x += y;
    }
    if (lane == 63) wsum[wv] = x;
    __syncthreads();
    if (wv == 0) {
        int s = (lane < 16) ? wsum[lane] : 0;
#pragma unroll
        for (int off = 1; off < 16; off <<= 1) {
            int y = __shfl_up(s, off, 64);
            if (lane >= off) s += y;
        }
        if (lane < 16) wpre[lane] = s;
    }
    __syncthreads();
    if (i < nb) bpre[i] = x - v + (wv ? wpre[wv - 1] : 0);
    if (threadIdx.x == 1023) offs[n] = wpre[15];
}

__global__ void scanC(const int* __restrict__ escan, const int* __restrict__ bpre,
                      int* __restrict__ offs, int* __restrict__ woff, int n) {
    int i = blockIdx.x * 256 + threadIdx.x;
    if (i >= n) return;
    int o = escan[i] + bpre[i >> 10];
    offs[i] = o;
    woff[i] = o;
}

__global__ void fill_kernel(const int* __restrict__ ei, int er, int etot,
                            int* __restrict__ woff, int* __restrict__ colv) {
    int e = blockIdx.x * blockDim.x + threadIdx.x;
    if (e >= etot) return;
    int src, dst;
    if (e < er) { src = ei[e]; dst = ei[er + e]; }
    else        { src = dst = e - er; }
    int pos = atomicAdd(&woff[dst], 1);
    colv[pos] = src;
}

// ---------------------------------------------------------------------------
// W -> per-MFMA-fragment bf16 hi/lo layout so gemm B-loads are coalesced.
// Wf[colblk(16)][ks(4)][lane(64)][j(8)]: value W[k][col],
//   col = colblk*16 + (lane&15), k = ks*32 + (lane>>4)*8 + j.
// colblk 0..7 = Wl cols, 8..15 = Wr cols.
// ---------------------------------------------------------------------------
__global__ void cvt_w(const float* __restrict__ Wl, const float* __restrict__ Wr,
                      ushort* __restrict__ Whi, ushort* __restrict__ Wlo) {
    int t = blockIdx.x * 256 + threadIdx.x;     // 0..32767
    int colblk = t >> 11;
    int ks = (t >> 9) & 3;
    int lane = (t >> 3) & 63;
    int j = t & 7;
    int col = colblk * 16 + (lane & 15);
    int k = ks * 32 + (lane >> 4) * 8 + j;
    float v = (col < 128) ? Wl[(size_t)k * 128 + col]
                          : Wr[(size_t)k * 128 + (col - 128)];
    ushort h = bf16_rne(v);
    Whi[t] = h;
    Wlo[t] = bf16_rne(v - bf16_to_f(h));
}

// ---------------------------------------------------------------------------
// Dual GEMM via split-bf16 MFMA. Block = 4 waves, 64-row tile.
// X tile staged in LDS (coalesced, XOR-swizzled 16B slots -> 2-way ds_read).
// B frags from pre-swizzled Wf (64-lane contiguous 1KB loads, L2-hot).
// wave w: cols [64w, 64w+64); waves 0,1 -> Ol, waves 2,3 -> Or.
// ---------------------------------------------------------------------------
__global__ __launch_bounds__(256) void gemm_mfma(
    const float* __restrict__ X,
    const ushort* __restrict__ Wfhi, const ushort* __restrict__ Wflo,
    float* __restrict__ Ol, float* __restrict__ Or, int nrows) {
    __shared__ float xs[64 * 128];              // 32 KiB, slot = row*32 + (kc^(row&7))
    const int t = threadIdx.x;
    const int wave = t >> 6, lane = t & 63;
    const int m0 = blockIdx.x * 64;
    {   // stage X tile: 2048 float4, 8 per thread, coalesced
        const float4* Xv = (const float4*)X + (size_t)m0 * 32;
        float4* xsv = (float4*)xs;
#pragma unroll
        for (int i = 0; i < 8; ++i) {
            int idx = i * 256 + t;
            int row = idx >> 5, kc = idx & 31;
            float4 v = {0.f, 0.f, 0.f, 0.f};
            if (m0 + row < nrows) v = Xv[idx];
            xsv[row * 32 + (kc ^ (row & 7))] = v;
        }
    }
    __syncthreads();

    const int lrow = lane & 15;
    const int lkc = (lane >> 4) * 2;            // 16B-slot offset within ks block
    f32x4 acc[4][4];
#pragma unroll
    for (int mt = 0; mt < 4; ++mt)
#pragma unroll
        for (int nt = 0; nt < 4; ++nt) acc[mt][nt] = (f32x4){0.f, 0.f, 0.f, 0.f};

#pragma unroll
    for (int ks = 0; ks < 4; ++ks) {
        short8 bhi[4], blo[4];
#pragma unroll
        for (int nt = 0; nt < 4; ++nt) {
            size_t off = (((size_t)(wave * 4 + nt) * 4 + ks) * 64 + lane) * 8;
            bhi[nt] = *(const short8*)&Wfhi[off];
            blo[nt] = *(const short8*)&Wflo[off];
        }
        short8 ahi[4], alo[4];
#pragma unroll
        for (int mt = 0; mt < 4; ++mt) {
            const int row = mt * 16 + lrow;
            const int kc0 = ks * 8 + lkc;
            float4 v0 = ((const float4*)xs)[row * 32 + (kc0 ^ (row & 7))];
            float4 v1 = ((const float4*)xs)[row * 32 + ((kc0 + 1) ^ (row & 7))];
            float e[8];
            e[0] = v0.x; e[1] = v0.y; e[2] = v0.z; e[3] = v0.w;
            e[4] = v1.x; e[5] = v1.y; e[6] = v1.z; e[7] = v1.w;
#pragma unroll
            for (int j = 0; j < 8; ++j) {
                ushort h = bf16_rne(e[j]);
                ahi[mt][j] = (short)h;
                alo[mt][j] = (short)bf16_rne(e[j] - bf16_to_f(h));
            }
        }
#pragma unroll
        for (int nt = 0; nt < 4; ++nt) {
#pragma unroll
            for (int mt = 0; mt < 4; ++mt) {
                acc[mt][nt] = __builtin_amdgcn_mfma_f32_16x16x32_bf16(
                    alo[mt], bhi[nt], acc[mt][nt], 0, 0, 0);
                acc[mt][nt] = __builtin_amdgcn_mfma_f32_16x16x32_bf16(
                    ahi[mt], blo[nt], acc[mt][nt], 0, 0, 0);
                acc[mt][nt] = __builtin_amdgcn_mfma_f32_16x16x32_bf16(
                    ahi[mt], bhi[nt], acc[mt][nt], 0, 0, 0);
            }
        }
    }
    // Epilogue. C/D frag: col = lane&15, row = (lane>>4)*4 + i  [m89 layout].
    float* __restrict__ O = (wave < 2) ? Ol : Or;
    const int cbase = (wave * 64) & 127;
    const int crow0 = (lane >> 4) * 4;
#pragma unroll
    for (int mt = 0; mt < 4; ++mt) {
#pragma unroll
        for (int i = 0; i < 4; ++i) {
            const int row = m0 + mt * 16 + crow0 + i;
            if (row >= nrows) continue;
#pragma unroll
            for (int nt = 0; nt < 4; ++nt) {
                const int col = cbase + nt * 16 + lrow;
                O[(size_t)row * 128 + col] = acc[mt][nt][i];
            }
        }
    }
}

// ---------------------------------------------------------------------------
// Fused GATv2 aggregation + bias + ELU + residual + LayerNorm.
// One wave per destination node; static grid-stride (NO atomics — round-4's
// single-address work-stealing counter serialized at the TCC, 8x regression).
// ---------------------------------------------------------------------------
__global__ __launch_bounds__(256) void gat_agg(
    const float* __restrict__ xl, const float* __restrict__ xr,
    const int* __restrict__ offs, const int* __restrict__ colv,
    const float* __restrict__ att,
    const float* __restrict__ bias, const float* __restrict__ gamma,
    const float* __restrict__ beta, const float* __restrict__ resid,
    float* __restrict__ out, int nnode) {
    const int lane = threadIdx.x & 63;
    const int wave0 = blockIdx.x * 4 + (threadIdx.x >> 6);
    const int wstride = gridDim.x * 4;
    const float2* __restrict__ xlb = (const float2*)xl + lane;
    const float2 att2 = ((const float2*)att)[lane];
    const float2 b2 = ((const float2*)bias)[lane];
    const float2 g2 = ((const float2*)gamma)[lane];
    const float2 be2 = ((const float2*)beta)[lane];
    for (int gid = wave0; gid < nnode; gid += wstride) {
        const float2 xr2 = ((const float2*)xr)[(size_t)gid * 64 + lane];
        float den = 0.f, acc0 = 0.f, acc1 = 0.f;
        int e = offs[gid];
        const int e1 = offs[gid + 1];
        for (; e + 4 <= e1; e += 4) {   // 4-edge unroll: MLP on the gather
            int s0 = colv[e], s1 = colv[e + 1], s2 = colv[e + 2], s3 = colv[e + 3];
            float2 a0 = xlb[(size_t)s0 * 64];
            float2 a1 = xlb[(size_t)s1 * 64];
            float2 a2 = xlb[(size_t)s2 * 64];
            float2 a3 = xlb[(size_t)s3 * 64];
            float m0x = a0.x + xr2.x, m0y = a0.y + xr2.y;
            float m1x = a1.x + xr2.x, m1y = a1.y + xr2.y;
            float m2x = a2.x + xr2.x, m2y = a2.y + xr2.y;
            float m3x = a3.x + xr2.x, m3y = a3.y + xr2.y;
            m0x = fmaxf(m0x, LEAKY * m0x); m0y = fmaxf(m0y, LEAKY * m0y);
            m1x = fmaxf(m1x, LEAKY * m1x); m1y = fmaxf(m1y, LEAKY * m1y);
            m2x = fmaxf(m2x, LEAKY * m2x); m2y = fmaxf(m2y, LEAKY * m2y);
            m3x = fmaxf(m3x, LEAKY * m3x); m3y = fmaxf(m3y, LEAKY * m3y);
            float p0 = m0x * att2.x + m0y * att2.y;
            float p1 = m1x * att2.x + m1y * att2.y;
            float p2 = m2x * att2.x + m2y * att2.y;
            float p3 = m3x * att2.x + m3y * att2.y;
            p0 += __shfl_xor(p0, 1); p0 += __shfl_xor(p0, 2); p0 += __shfl_xor(p0, 4);
            p1 += __shfl_xor(p1, 1); p1 += __shfl_xor(p1, 2); p1 += __shfl_xor(p1, 4);
            p2 += __shfl_xor(p2, 1); p2 += __shfl_xor(p2, 2); p2 += __shfl_xor(p2, 4);
            p3 += __shfl_xor(p3, 1); p3 += __shfl_xor(p3, 2); p3 += __shfl_xor(p3, 4);
            float ex0 = __expf(p0), ex1 = __expf(p1);
            float ex2 = __expf(p2), ex3 = __expf(p3);
            den += (ex0 + ex1) + (ex2 + ex3);
            acc0 += a0.x * ex0 + a1.x * ex1 + a2.x * ex2 + a3.x * ex3;
            acc1 += a0.y * ex0 + a1.y * ex1 + a2.y * ex2 + a3.y * ex3;
        }
        for (; e < e1; ++e) {
            int s0 = colv[e];
            float2 a0 = xlb[(size_t)s0 * 64];
            float m0x = a0.x + xr2.x, m0y = a0.y + xr2.y;
            m0x = fmaxf(m0x, LEAKY * m0x);
            m0y = fmaxf(m0y, LEAKY * m0y);
            float p0 = m0x * att2.x + m0y * att2.y;
            p0 += __shfl_xor(p0, 1); p0 += __shfl_xor(p0, 2); p0 += __shfl_xor(p0, 4);
            float ex0 = __expf(p0);
            den += ex0;
            acc0 += a0.x * ex0;
            acc1 += a0.y * ex0;
        }
        float inv_den = 1.f / den;
        float v0 = acc0 * inv_den + b2.x;
        float v1 = acc1 * inv_den + b2.y;
        v0 = v0 > 0.f ? v0 : expm1f(v0);     // ELU (alpha=1)
        v1 = v1 > 0.f ? v1 : expm1f(v1);
        const float2 r2 = ((const float2*)resid)[(size_t)gid * 64 + lane];
        float t0 = v0 + r2.x, t1 = v1 + r2.y;
        float s = t0 + t1, ss = t0 * t0 + t1 * t1;
#pragma unroll
        for (int m = 1; m < 64; m <<= 1) {
            s += __shfl_xor(s, m);
            ss += __shfl_xor(ss, m);
        }
        const float mu = s * 0.0078125f;
        const float var = ss * 0.0078125f - mu * mu;
        const float iv = rsqrtf(var + LN_EPS);
        float2 o;
        o.x = (t0 - mu) * iv * g2.x + be2.x;
        o.y = (t1 - mu) * iv * g2.y + be2.y;
        ((float2*)out)[(size_t)gid * 64 + lane] = o;
    }
}

// ---------------------------------------------------------------------------
extern "C" void kernel_launch(void* const* d_in, const int* in_sizes, int n_in,
                              void* d_out, int out_size, void* d_ws, size_t ws_size,
                              hipStream_t stream) {
    const float* x   = (const float*)d_in[0];
    const int*   ei  = (const int*)d_in[1];
    const float* Wl0 = (const float*)d_in[2];
    const float* Wr0 = (const float*)d_in[3];
    const float* at0 = (const float*)d_in[4];
    const float* b0  = (const float*)d_in[5];
    const float* g0  = (const float*)d_in[6];
    const float* be0 = (const float*)d_in[7];
    const float* Wl1 = (const float*)d_in[8];
    const float* Wr1 = (const float*)d_in[9];
    const float* at1 = (const float*)d_in[10];
    const float* b1  = (const float*)d_in[11];
    const float* g1  = (const float*)d_in[12];
    const float* be1 = (const float*)d_in[13];

    const int NF = in_sizes[0];        // N*128
    const int n  = NF / 128;           // nodes
    const int er = in_sizes[1] / 2;    // raw edges
    const int etot = er + n;           // + self-loops
    const int nb = (n + 1023) / 1024;  // scan blocks

    float* A    = (float*)d_ws;        // xl  (N*128)
    float* B    = A + (size_t)NF;      // xr  (N*128)
    ushort* Whi = (ushort*)(B + (size_t)NF);   // 32768 bf16 hi (frag layout)
    ushort* Wlo = Whi + 32768;                 // 32768 bf16 lo
    int* deg    = (int*)(Wlo + 32768);
    int* woff   = deg + n;
    int* offs   = woff + n;
    int* escan  = offs + (n + 1);
    int* bsum   = escan + n;
    int* bpre   = bsum + 1024;
    int* colv   = bpre + 1024;
    float* C    = (float*)d_out;       // layer-1 output / residual / final out

    // ---- CSR build (shared by both layers) ----
    hipMemsetAsync(deg, 0, (size_t)n * sizeof(int), stream);
    hist_kernel<<<(etot + 255) / 256, 256, 0, stream>>>(ei, er, etot, deg);
    scanA<<<nb, 1024, 0, stream>>>(deg, escan, bsum, n);
    scanB<<<1, 1024, 0, stream>>>(bsum, bpre, nb, offs, n);
    scanC<<<(n + 255) / 256, 256, 0, stream>>>(escan, bpre, offs, woff, n);
    fill_kernel<<<(etot + 255) / 256, 256, 0, stream>>>(ei, er, etot, woff, colv);

    const int gblk = (n + 63) / 64;

    // ---- layer 1 ----
    cvt_w<<<128, 256, 0, stream>>>(Wl0, Wr0, Whi, Wlo);
    gemm_mfma<<<gblk, 256, 0, stream>>>(x, Whi, Wlo, A, B, n);
    gat_agg<<<2048, 256, 0, stream>>>(A, B, offs, colv, at0, b0, g0, be0,
                                      x, C, n);
    // ---- layer 2 ----
    cvt_w<<<128, 256, 0, stream>>>(Wl1, Wr1, Whi, Wlo);
    gemm_mfma<<<gblk, 256, 0, stream>>>(C, Whi, Wlo, A, B, n);
    gat_agg<<<2048, 256, 0, stream>>>(A, B, offs, colv, at1, b1, g1, be1,
                                      C, C, n);
}